// Round 7
// baseline (191.806 us; speedup 1.0000x reference)
//
#include <hip/hip_runtime.h>
#include <cstdint>

typedef short bf16x8 __attribute__((ext_vector_type(8)));
typedef float f32x4 __attribute__((ext_vector_type(4)));
typedef unsigned short u16;
typedef unsigned int u32;

#define DEVI static __device__ __forceinline__

// ---------- helpers ----------

DEVI u16 f2bf(float f) {              // fp32 -> bf16 RTNE (inputs are finite)
  u32 x = __builtin_bit_cast(u32, f);
  x += 0x7fffu + ((x >> 16) & 1u);
  return (u16)(x >> 16);
}

DEVI u32 pack_bf2(float lo, float hi) {
  return (u32)f2bf(lo) | ((u32)f2bf(hi) << 16);
}

DEVI u32 cvt_pk_bf16(float lo, float hi) {
  u32 r;
  asm("v_cvt_pk_bf16_f32 %0, %1, %2" : "=v"(r) : "v"(lo), "v"(hi));
  return r;
}

DEVI f32x4 mfma16(bf16x8 a, bf16x8 b, f32x4 c) {
  return __builtin_amdgcn_mfma_f32_16x16x32_bf16(a, b, c, 0, 0, 0);
}

DEVI void load_lds16(const void* g, void* l) {   // 16B per lane, dest = base + lane*16
  __builtin_amdgcn_global_load_lds(
      (const __attribute__((address_space(1))) u32*)g,
      (__attribute__((address_space(3))) u32*)l, 16, 0, 0);
}

// CSCALE = log2(e) / sqrt(DK=32): folded into Q so attention uses raw exp2
#define CSCALE 0.2550351f

// key-row permutation within each 64-key tile (swapped-QK a-frag alignment)
DEVI int rho(int k) {
  return ((k >> 5) << 5) | (((k >> 2) & 1) << 4) | (((k >> 3) & 3) << 2) | (k & 3);
}

// ---------- kernel 1: fp32 -> bf16 conversion ----------
__global__ __launch_bounds__(256) void convert_kernel(
    const float* __restrict__ xa, const float* __restrict__ xb,
    const float* __restrict__ w0, const float* __restrict__ w1,
    const float* __restrict__ w2, const float* __restrict__ w3,
    const float* __restrict__ w4, const float* __restrict__ w5,
    u16* __restrict__ dst) {
  int i = (int)(blockIdx.x * 256u + threadIdx.x) * 8;
  const float* s;
  if (i < 1048576) {
    s = xa + i;
  } else if (i < 2097152) {
    s = xb + (i - 1048576);
  } else {
    int t = i - 2097152;
    int j = t >> 16, o = t & 65535;
    s = (j == 0 ? w0 : j == 1 ? w1 : j == 2 ? w2 : j == 3 ? w3 : j == 4 ? w4 : w5) + o;
  }
  float4 a = *(const float4*)s;
  float4 b = *(const float4*)(s + 4);
  uint4 o4;
  o4.x = pack_bf2(a.x, a.y);
  o4.y = pack_bf2(a.z, a.w);
  o4.z = pack_bf2(b.x, b.y);
  o4.w = pack_bf2(b.z, b.w);
  *(uint4*)(dst + i) = o4;
}

// ---------- kernel 2: fused projections (5 jobs) ----------
__global__ __launch_bounds__(256) void proj_kernel(
    const u16* __restrict__ xa_bf, const u16* __restrict__ xb_bf,
    const u16* __restrict__ wbase,
    const float* __restrict__ b0, const float* __restrict__ b1,
    const float* __restrict__ b2, const float* __restrict__ b3,
    const float* __restrict__ b4,
    u16* __restrict__ Qo, u16* __restrict__ Ko, u16* __restrict__ Vo) {
  int job = blockIdx.z;
  const u16* A = (job <= 2) ? xa_bf : xb_bf;
  const u16* W = wbase + job * 65536;
  const float* bias = job == 0 ? b0 : job == 1 ? b1 : job == 2 ? b2 : job == 3 ? b3 : b4;
  int mode = (job == 0) ? 0 : (job == 1 || job == 3) ? 1 : 2;
  int soff = (job >= 3) ? 2048 : 0;

  int tid = threadIdx.x, wid = tid >> 6, lane = tid & 63, g = lane >> 4, c = lane & 15;
  int m0 = blockIdx.x * 64, n0 = blockIdx.y * 64;
  const u16* Ap = A + (size_t)(m0 + wid * 16 + c) * 256 + g * 8;
  const u16* Wp = W + (n0 + c) * 256 + g * 8;
  f32x4 acc[4] = {};
#pragma unroll
  for (int kk = 0; kk < 256; kk += 32) {
    bf16x8 af = *(const bf16x8*)(Ap + kk);
#pragma unroll
    for (int nt = 0; nt < 4; ++nt) {
      bf16x8 bfr = *(const bf16x8*)(Wp + nt * 4096 + kk);
      acc[nt] = mfma16(af, bfr, acc[nt]);
    }
  }
#pragma unroll
  for (int nt = 0; nt < 4; ++nt) {
    int f = n0 + nt * 16 + c;
    float bv = bias[f];
    int h = f >> 5, d = f & 31;
#pragma unroll
    for (int r = 0; r < 4; ++r) {
      int m = m0 + wid * 16 + g * 4 + r;
      int bq = m >> 11, n = m & 2047;
      int bh = bq * 8 + h;
      float y = acc[nt][r] + bv;
      if (mode == 0) {
        Qo[((size_t)bh * 2048 + n) * 32 + d] = f2bf(y * CSCALE);
      } else if (mode == 1) {
        int nk = soff + n;
        int pr = (nk & ~63) | rho(nk & 63);
        Ko[((size_t)bh * 4096 + pr) * 32 + d] = f2bf(y);
      } else {
        int nk = soff + n;
        // V layout: [bh][tile=nk>>6][unit=(nk>>3)&7][d][nk&7], u16 units
        Vo[(size_t)bh * 131072 + (nk >> 6) * 2048 + ((nk >> 3) & 7) * 256 +
           d * 8 + (nk & 7)] = f2bf(y);
      }
    }
  }
}

// ---------- kernel 3: flash attention, 64 q-rows/wave, split-K x4 ----------
__global__ __launch_bounds__(256) void attn_kernel(
    const u16* __restrict__ Q, const u16* __restrict__ K,
    const u16* __restrict__ Vt, float* __restrict__ Zp, float* __restrict__ S) {
  __shared__ __align__(16) unsigned char sbuf[24576];
  int bid = blockIdx.x;
  int xcd = bid & 7, slot = bid >> 3;
  int bh = (xcd << 1) | (slot & 1);
  int rem = slot >> 1;
  int ks = rem & 3, qi = rem >> 2;
  int tid = threadIdx.x, wid = tid >> 6, lane = tid & 63;
  int g = lane >> 4, c = lane & 15;
  int qbase = qi * 256 + wid * 64;

  const unsigned char* Kb =
      (const unsigned char*)K + (size_t)bh * 262144 + (size_t)ks * 65536;
  const unsigned char* Vb =
      (const unsigned char*)Vt + (size_t)bh * 262144 + (size_t)ks * 65536;

  const u16* Qp = Q + ((size_t)bh * 2048 + qbase + c) * 32 + g * 8;
  bf16x8 qf0 = *(const bf16x8*)(Qp);
  bf16x8 qf1 = *(const bf16x8*)(Qp + 16 * 32);
  bf16x8 qf2 = *(const bf16x8*)(Qp + 32 * 32);
  bf16x8 qf3 = *(const bf16x8*)(Qp + 48 * 32);

  int kaddr = c * 64 + ((g ^ ((c >> 1) & 3)) << 4);   // + s*1024
  int vaddr = g * 512 + c * 16;                        // +256 d-hi; +2048 key-hi

  int o = wid * 1024 + (lane << 4);
  int ko_src = o ^ (((o >> 7) & 3) << 4);

  const u32 one2 = 0x3F803F80u;  // two bf16 1.0
  union { u32 u[4]; bf16x8 v; } ones;
  ones.u[0] = one2; ones.u[1] = one2; ones.u[2] = one2; ones.u[3] = one2;

  f32x4 z00 = {}, z01 = {}, z10 = {}, z11 = {};
  f32x4 z20 = {}, z21 = {}, z30 = {}, z31 = {};
  f32x4 zs0 = {}, zs1 = {}, zs2 = {}, zs3 = {};

  load_lds16(Kb + ko_src, sbuf + wid * 1024);
  load_lds16(Vb + o, sbuf + 12288 + wid * 1024);

  int cur = 0;
  for (int t = 0; t < 16; ++t) {
    int nxt = cur + 1;
    if (nxt == 3) nxt = 0;
    if (t + 1 < 16) {
      load_lds16(Kb + (t + 1) * 4096 + ko_src, sbuf + nxt * 4096 + wid * 1024);
      load_lds16(Vb + (t + 1) * 4096 + o, sbuf + 12288 + nxt * 4096 + wid * 1024);
      __builtin_amdgcn_sched_barrier(0);
      asm volatile("s_waitcnt vmcnt(2)" ::: "memory");
    } else {
      __builtin_amdgcn_sched_barrier(0);
      asm volatile("s_waitcnt vmcnt(0)" ::: "memory");
    }
    __builtin_amdgcn_s_barrier();
    __builtin_amdgcn_sched_barrier(0);

    const unsigned char* kbuf = sbuf + cur * 4096;
    const unsigned char* vbuf = sbuf + 12288 + cur * 4096;

    bf16x8 kf0 = *(const bf16x8*)(kbuf + kaddr);
    bf16x8 kf1 = *(const bf16x8*)(kbuf + kaddr + 1024);
    bf16x8 kf2 = *(const bf16x8*)(kbuf + kaddr + 2048);
    bf16x8 kf3 = *(const bf16x8*)(kbuf + kaddr + 3072);
    bf16x8 vf00 = *(const bf16x8*)(vbuf + vaddr);
    bf16x8 vf01 = *(const bf16x8*)(vbuf + vaddr + 2048);
    bf16x8 vf10 = *(const bf16x8*)(vbuf + vaddr + 256);
    bf16x8 vf11 = *(const bf16x8*)(vbuf + vaddr + 2048 + 256);

#define QFRAG(QF, ZA, ZB, ZS)                                              \
    {                                                                      \
      f32x4 zz = {};                                                       \
      __builtin_amdgcn_s_setprio(1);                                       \
      f32x4 s0 = mfma16(kf0, QF, zz);                                      \
      f32x4 s1 = mfma16(kf1, QF, zz);                                      \
      f32x4 s2 = mfma16(kf2, QF, zz);                                      \
      f32x4 s3 = mfma16(kf3, QF, zz);                                      \
      __builtin_amdgcn_s_setprio(0);                                       \
      float e0[4], e1[4], e2[4], e3[4];                                    \
      _Pragma("unroll")                                                    \
      for (int r = 0; r < 4; ++r) {                                        \
        e0[r] = __builtin_amdgcn_exp2f(s0[r]);                             \
        e1[r] = __builtin_amdgcn_exp2f(s1[r]);                             \
        e2[r] = __builtin_amdgcn_exp2f(s2[r]);                             \
        e3[r] = __builtin_amdgcn_exp2f(s3[r]);                             \
      }                                                                    \
      union { u32 u[4]; bf16x8 v; } A0, A1;                                \
      A0.u[0] = cvt_pk_bf16(e0[0], e0[1]);                                 \
      A0.u[1] = cvt_pk_bf16(e0[2], e0[3]);                                 \
      A0.u[2] = cvt_pk_bf16(e1[0], e1[1]);                                 \
      A0.u[3] = cvt_pk_bf16(e1[2], e1[3]);                                 \
      A1.u[0] = cvt_pk_bf16(e2[0], e2[1]);                                 \
      A1.u[1] = cvt_pk_bf16(e2[2], e2[3]);                                 \
      A1.u[2] = cvt_pk_bf16(e3[0], e3[1]);                                 \
      A1.u[3] = cvt_pk_bf16(e3[2], e3[3]);                                 \
      __builtin_amdgcn_s_setprio(1);                                       \
      ZA = mfma16(A0.v, vf00, ZA);                                         \
      ZA = mfma16(A1.v, vf01, ZA);                                         \
      ZB = mfma16(A0.v, vf10, ZB);                                         \
      ZB = mfma16(A1.v, vf11, ZB);                                         \
      ZS = mfma16(A0.v, ones.v, ZS);                                       \
      ZS = mfma16(A1.v, ones.v, ZS);                                       \
      __builtin_amdgcn_s_setprio(0);                                       \
    }

    QFRAG(qf0, z00, z01, zs0)
    QFRAG(qf1, z10, z11, zs1)
    QFRAG(qf2, z20, z21, zs2)
    QFRAG(qf3, z30, z31, zs3)
#undef QFRAG
    cur = nxt;
  }

  size_t zrow = ((size_t)ks * 16 + bh) * 2048;
#define STORE(J, ZA, ZB, ZS)                                               \
  _Pragma("unroll")                                                        \
  for (int r = 0; r < 4; ++r) {                                            \
    int m = qbase + J * 16 + g * 4 + r;                                    \
    float* zp = Zp + (zrow + m) * 32;                                      \
    zp[c] = ZA[r];                                                         \
    zp[16 + c] = ZB[r];                                                    \
    if (c == 0) S[zrow + m] = ZS[r];                                       \
  }
  STORE(0, z00, z01, zs0)
  STORE(1, z10, z11, zs1)
  STORE(2, z20, z21, zs2)
  STORE(3, z30, z31, zs3)
#undef STORE
}

// ---------- kernel 4: combine(4 splits) + out = Z @ w^T + b + x_a (fp32) -------
__global__ __launch_bounds__(256) void out_kernel(
    const float* __restrict__ Zp, const float* __restrict__ S,
    const u16* __restrict__ W, const float* __restrict__ bias,
    const float* __restrict__ resid, float* __restrict__ out) {
  int tid = threadIdx.x, wid = tid >> 6, lane = tid & 63, g = lane >> 4, c = lane & 15;
  int m0 = blockIdx.x * 16;
  int mrow = m0 + c;
  int bq = mrow >> 11, n = mrow & 2047;
  const u16* Wp = W + (size_t)(wid * 64 + c) * 256 + g * 8;

  f32x4 acc[4] = {};
#pragma unroll
  for (int h = 0; h < 8; ++h) {
    int bh = bq * 8 + h;
    size_t sb = (size_t)bh * 2048 + n;
    float ts = (S[sb] + S[sb + 32768]) + (S[sb + 65536] + S[sb + 98304]);
    float iv = 1.0f / ts;
    const float* zp = Zp + sb * 32 + g * 8;
    float4 a0 = *(const float4*)zp;
    float4 a1 = *(const float4*)(zp + 4);
    float4 b0 = *(const float4*)(zp + 1048576);
    float4 b1 = *(const float4*)(zp + 1048576 + 4);
    float4 c0 = *(const float4*)(zp + 2097152);
    float4 c1 = *(const float4*)(zp + 2097152 + 4);
    float4 d0 = *(const float4*)(zp + 3145728);
    float4 d1 = *(const float4*)(zp + 3145728 + 4);
    float e0 = ((a0.x + b0.x) + (c0.x + d0.x)) * iv;
    float e1 = ((a0.y + b0.y) + (c0.y + d0.y)) * iv;
    float e2 = ((a0.z + b0.z) + (c0.z + d0.z)) * iv;
    float e3 = ((a0.w + b0.w) + (c0.w + d0.w)) * iv;
    float e4 = ((a1.x + b1.x) + (c1.x + d1.x)) * iv;
    float e5 = ((a1.y + b1.y) + (c1.y + d1.y)) * iv;
    float e6 = ((a1.z + b1.z) + (c1.z + d1.z)) * iv;
    float e7 = ((a1.w + b1.w) + (c1.w + d1.w)) * iv;
    union { u32 u[4]; bf16x8 v; } af;
    af.u[0] = cvt_pk_bf16(e0, e1);
    af.u[1] = cvt_pk_bf16(e2, e3);
    af.u[2] = cvt_pk_bf16(e4, e5);
    af.u[3] = cvt_pk_bf16(e6, e7);
#pragma unroll
    for (int nt = 0; nt < 4; ++nt) {
      bf16x8 bfr = *(const bf16x8*)(Wp + nt * 4096 + h * 32);
      acc[nt] = mfma16(af.v, bfr, acc[nt]);
    }
  }
#pragma unroll
  for (int nt = 0; nt < 4; ++nt) {
    int f = wid * 64 + nt * 16 + c;
    float bv = bias[f];
#pragma unroll
    for (int r = 0; r < 4; ++r) {
      int m = m0 + g * 4 + r;
      out[(size_t)m * 256 + f] = acc[nt][r] + bv + resid[(size_t)m * 256 + f];
    }
  }
}

// ---------- launch ----------
// MEASUREMENT ROUND: pipeline is idempotent; attn launched 5x total so that
// dur_us - dur_us(round6) = 4 * (attn + launch overhead). Decision rules in
// the journal; this isolates attn's true share (rocprof top-5 is clogged by
// 42us harness poison fills, so attn hasn't been directly measured since r2).
extern "C" void kernel_launch(void* const* d_in, const int* in_sizes, int n_in,
                              void* d_out, int out_size, void* d_ws, size_t ws_size,
                              hipStream_t stream) {
  const float* xa = (const float*)d_in[0];
  const float* xb = (const float*)d_in[1];
  const float* wq_w = (const float*)d_in[2];
  const float* wq_b = (const float*)d_in[3];
  const float* wka_w = (const float*)d_in[4];
  const float* wka_b = (const float*)d_in[5];
  const float* wkb_w = (const float*)d_in[6];
  const float* wkb_b = (const float*)d_in[7];
  const float* wva_w = (const float*)d_in[8];
  const float* wva_b = (const float*)d_in[9];
  const float* wvb_w = (const float*)d_in[10];
  const float* wvb_b = (const float*)d_in[11];
  const float* w_w = (const float*)d_in[12];
  const float* w_b = (const float*)d_in[13];

  u16* ws = (u16*)d_ws;
  u16* xa_bf = ws;                  // 1048576
  u16* xb_bf = ws + 1048576;        // 1048576
  u16* wbf = ws + 2097152;          // 6 * 65536
  u16* Qb = ws + 2490368;           // 1048576
  u16* Kb = ws + 3538944;           // 2097152
  u16* Vtb = ws + 5636096;          // 2097152
  float* Zp = (float*)(ws + 7733248);   // 4*16*2048*32 fp32 = 16 MB
  float* S = Zp + 4194304;              // 4*16*2048 fp32 = 512 KB

  convert_kernel<<<1216, 256, 0, stream>>>(xa, xb, wq_w, wka_w, wva_w, wkb_w,
                                           wvb_w, w_w, ws);
  proj_kernel<<<dim3(64, 4, 5), 256, 0, stream>>>(
      xa_bf, xb_bf, wbf, wq_b, wka_b, wva_b, wkb_b, wvb_b, Qb, Kb, Vtb);
  attn_kernel<<<512, 256, 0, stream>>>(Qb, Kb, Vtb, Zp, S);
  attn_kernel<<<512, 256, 0, stream>>>(Qb, Kb, Vtb, Zp, S);
  attn_kernel<<<512, 256, 0, stream>>>(Qb, Kb, Vtb, Zp, S);
  attn_kernel<<<512, 256, 0, stream>>>(Qb, Kb, Vtb, Zp, S);
  attn_kernel<<<512, 256, 0, stream>>>(Qb, Kb, Vtb, Zp, S);
  out_kernel<<<256, 256, 0, stream>>>(Zp, S, wbf + 5 * 65536, w_b, xa,
                                      (float*)d_out);
}

// Round 8
// 79.219 us; speedup vs baseline: 2.4212x; 2.4212x over previous
//
#include <hip/hip_runtime.h>
#include <cstdint>

typedef short bf16x8 __attribute__((ext_vector_type(8)));
typedef float f32x4 __attribute__((ext_vector_type(4)));
typedef unsigned short u16;
typedef unsigned int u32;

#define DEVI static __device__ __forceinline__

// ---------- helpers ----------

DEVI u16 f2bf(float f) {              // fp32 -> bf16 RTNE (inputs are finite)
  u32 x = __builtin_bit_cast(u32, f);
  x += 0x7fffu + ((x >> 16) & 1u);
  return (u16)(x >> 16);
}

DEVI u32 pack_bf2(float lo, float hi) {
  return (u32)f2bf(lo) | ((u32)f2bf(hi) << 16);
}

DEVI u32 cvt_pk_bf16(float lo, float hi) {
  u32 r;
  asm("v_cvt_pk_bf16_f32 %0, %1, %2" : "=v"(r) : "v"(lo), "v"(hi));
  return r;
}

DEVI f32x4 mfma16(bf16x8 a, bf16x8 b, f32x4 c) {
  return __builtin_amdgcn_mfma_f32_16x16x32_bf16(a, b, c, 0, 0, 0);
}

// CSCALE = log2(e) / sqrt(DK=32): folded into Q so attention uses raw exp2
#define CSCALE 0.2550351f

// key-row permutation within each 64-key tile (swapped-QK a-frag alignment)
DEVI int rho(int k) {
  return ((k >> 5) << 5) | (((k >> 2) & 1) << 4) | (((k >> 3) & 3) << 2) | (k & 3);
}

// ---------- kernel 1: fp32 -> bf16 conversion ----------
__global__ __launch_bounds__(256) void convert_kernel(
    const float* __restrict__ xa, const float* __restrict__ xb,
    const float* __restrict__ w0, const float* __restrict__ w1,
    const float* __restrict__ w2, const float* __restrict__ w3,
    const float* __restrict__ w4, const float* __restrict__ w5,
    u16* __restrict__ dst) {
  int i = (int)(blockIdx.x * 256u + threadIdx.x) * 8;
  const float* s;
  if (i < 1048576) {
    s = xa + i;
  } else if (i < 2097152) {
    s = xb + (i - 1048576);
  } else {
    int t = i - 2097152;
    int j = t >> 16, o = t & 65535;
    s = (j == 0 ? w0 : j == 1 ? w1 : j == 2 ? w2 : j == 3 ? w3 : j == 4 ? w4 : w5) + o;
  }
  float4 a = *(const float4*)s;
  float4 b = *(const float4*)(s + 4);
  uint4 o4;
  o4.x = pack_bf2(a.x, a.y);
  o4.y = pack_bf2(a.z, a.w);
  o4.z = pack_bf2(b.x, b.y);
  o4.w = pack_bf2(b.z, b.w);
  *(uint4*)(dst + i) = o4;
}

// ---------- kernel 2: fused projections (5 jobs), coalesced 8B stores ----------
// jobs: 0 = Q(x_a,wq)*CSCALE -> [BH,2048,32]         (swapped orientation)
//       1 = K(x_a,wk_a) -> [BH,4096,32] rho-permuted (swapped orientation)
//       2 = V(x_a,wv_a) -> [BH,32 d,4096 keys] d-major (original orientation)
//       3 = K(x_b,wk_b) rows 2048..4095
//       4 = V(x_b,wv_b) cols 2048..4095
// Swapped orientation: mfma(W,x) -> thread holds 4 consecutive f (=d) at one
// row m -> uint2 (4xbf16) stores. Original: 4 consecutive keys at one d.
__global__ __launch_bounds__(256) void proj_kernel(
    const u16* __restrict__ xa_bf, const u16* __restrict__ xb_bf,
    const u16* __restrict__ wbase,
    const float* __restrict__ b0, const float* __restrict__ b1,
    const float* __restrict__ b2, const float* __restrict__ b3,
    const float* __restrict__ b4,
    u16* __restrict__ Qo, u16* __restrict__ Ko, u16* __restrict__ Vo) {
  int job = blockIdx.z;
  const u16* A = (job <= 2) ? xa_bf : xb_bf;
  const u16* W = wbase + job * 65536;
  const float* bias = job == 0 ? b0 : job == 1 ? b1 : job == 2 ? b2 : job == 3 ? b3 : b4;
  int mode = (job == 0) ? 0 : (job == 1 || job == 3) ? 1 : 2;
  int soff = (job >= 3) ? 2048 : 0;

  int tid = threadIdx.x, wid = tid >> 6, lane = tid & 63, g = lane >> 4, c = lane & 15;
  int m0 = blockIdx.x * 64, n0 = blockIdx.y * 64;
  const u16* Ap = A + (size_t)(m0 + wid * 16 + c) * 256 + g * 8;
  const u16* Wp = W + (n0 + c) * 256 + g * 8;
  f32x4 acc[4] = {};
  if (mode == 2) {  // original: out rows = x-rows
#pragma unroll
    for (int kk = 0; kk < 256; kk += 32) {
      bf16x8 af = *(const bf16x8*)(Ap + kk);
#pragma unroll
      for (int nt = 0; nt < 4; ++nt) {
        bf16x8 bfr = *(const bf16x8*)(Wp + nt * 4096 + kk);
        acc[nt] = mfma16(af, bfr, acc[nt]);
      }
    }
  } else {  // swapped: out rows = W-rows (f)
#pragma unroll
    for (int kk = 0; kk < 256; kk += 32) {
      bf16x8 af = *(const bf16x8*)(Ap + kk);
#pragma unroll
      for (int nt = 0; nt < 4; ++nt) {
        bf16x8 bfr = *(const bf16x8*)(Wp + nt * 4096 + kk);
        acc[nt] = mfma16(bfr, af, acc[nt]);
      }
    }
  }

  if (mode == 2) {
    // thread: fixed f (=h,d), keys mb..mb+3 -> V[bh][d][key] 8B store
    int mb = m0 + wid * 16 + g * 4;
    int bq = mb >> 11;
    int nk = soff + (mb & 2047);
#pragma unroll
    for (int nt = 0; nt < 4; ++nt) {
      int f = n0 + nt * 16 + c;
      int h = f >> 5, d = f & 31;
      float bv = bias[f];
      int bh = bq * 8 + h;
      uint2 pw;
      pw.x = pack_bf2(acc[nt][0] + bv, acc[nt][1] + bv);
      pw.y = pack_bf2(acc[nt][2] + bv, acc[nt][3] + bv);
      *(uint2*)(Vo + (size_t)(bh * 32 + d) * 4096 + nk) = pw;
    }
  } else {
    // thread: fixed row m, f = fb..fb+3 (4 consecutive d) -> 8B store
    int m = m0 + wid * 16 + c;
    int bq = m >> 11, n = m & 2047;
#pragma unroll
    for (int nt = 0; nt < 4; ++nt) {
      int fb = n0 + nt * 16 + g * 4;
      int h = fb >> 5, db = fb & 31;
      int bh = bq * 8 + h;
      float4 bv4 = *(const float4*)(bias + fb);
      float v0 = acc[nt][0] + bv4.x;
      float v1 = acc[nt][1] + bv4.y;
      float v2 = acc[nt][2] + bv4.z;
      float v3 = acc[nt][3] + bv4.w;
      uint2 pw;
      u16* dst;
      if (mode == 0) {
        pw.x = pack_bf2(v0 * CSCALE, v1 * CSCALE);
        pw.y = pack_bf2(v2 * CSCALE, v3 * CSCALE);
        dst = Qo + ((size_t)bh * 2048 + n) * 32 + db;
      } else {
        int nk = soff + n;
        int pr = (nk & ~63) | rho(nk & 63);
        pw.x = pack_bf2(v0, v1);
        pw.y = pack_bf2(v2, v3);
        dst = Ko + ((size_t)bh * 4096 + pr) * 32 + db;
      }
      *(uint2*)dst = pw;
    }
  }
}

// ---------- kernel 3: barrier-free flash attention ----------
// grid 512: xcd=bid&7, slot=bid>>3; bh=(xcd<<1)|(slot&1); rem=slot>>1:
// ks=rem&3 (key quarter), qi=rem>>2. 4 waves x 64 q-rows, NO LDS, NO barriers.
// K/V read per-wave directly from global (L2-resident per XCD: 2 heads = 1MB),
// double-buffered register prefetch. P in registers; row-sums via ones-MFMA.
__global__ __launch_bounds__(256) void attn_kernel(
    const u16* __restrict__ Q, const u16* __restrict__ K,
    const u16* __restrict__ V, float* __restrict__ Zp, float* __restrict__ S) {
  int bid = blockIdx.x;
  int xcd = bid & 7, slot = bid >> 3;
  int bh = (xcd << 1) | (slot & 1);
  int rem = slot >> 1;
  int ks = rem & 3, qi = rem >> 2;
  int tid = threadIdx.x, wid = tid >> 6, lane = tid & 63;
  int g = lane >> 4, c = lane & 15;
  int qbase = qi * 256 + wid * 64;

  const u16* Kb = K + (size_t)bh * 131072 + (size_t)ks * 32768;  // [1024 keys][32 d]
  const u16* Vb = V + (size_t)bh * 131072 + (size_t)ks * 1024;   // [32 d][4096 keys]

  const u16* Qp = Q + ((size_t)bh * 2048 + qbase + c) * 32 + g * 8;
  bf16x8 qf0 = *(const bf16x8*)(Qp);
  bf16x8 qf1 = *(const bf16x8*)(Qp + 16 * 32);
  bf16x8 qf2 = *(const bf16x8*)(Qp + 32 * 32);
  bf16x8 qf3 = *(const bf16x8*)(Qp + 48 * 32);

  int koff = c * 32 + g * 8;                 // + s*512 + t*2048 (u16 units)
  size_t voff = (size_t)c * 4096 + g * 8;    // + t*64; +65536 d-hi; +32 key-hi

  const u32 one2 = 0x3F803F80u;  // two bf16 1.0
  union { u32 u[4]; bf16x8 v; } ones;
  ones.u[0] = one2; ones.u[1] = one2; ones.u[2] = one2; ones.u[3] = one2;

  f32x4 z00 = {}, z01 = {}, z10 = {}, z11 = {};
  f32x4 z20 = {}, z21 = {}, z30 = {}, z31 = {};
  f32x4 zs0 = {}, zs1 = {}, zs2 = {}, zs3 = {};

  bf16x8 ka0, ka1, ka2, ka3, va00, va01, va10, va11;
  bf16x8 kb0, kb1, kb2, kb3, vb00, vb01, vb10, vb11;

#define LOADT(T, K0, K1, K2, K3, V00, V01, V10, V11)                        \
  K0 = *(const bf16x8*)(Kb + (T) * 2048 + koff);                            \
  K1 = *(const bf16x8*)(Kb + (T) * 2048 + 512 + koff);                      \
  K2 = *(const bf16x8*)(Kb + (T) * 2048 + 1024 + koff);                     \
  K3 = *(const bf16x8*)(Kb + (T) * 2048 + 1536 + koff);                     \
  V00 = *(const bf16x8*)(Vb + voff + (T) * 64);                             \
  V01 = *(const bf16x8*)(Vb + voff + (T) * 64 + 32);                        \
  V10 = *(const bf16x8*)(Vb + voff + 65536 + (T) * 64);                     \
  V11 = *(const bf16x8*)(Vb + voff + 65536 + (T) * 64 + 32);

#define QFRAG(QF, KF0, KF1, KF2, KF3, VF00, VF01, VF10, VF11, ZA, ZB, ZS)  \
    {                                                                      \
      f32x4 zz = {};                                                       \
      __builtin_amdgcn_s_setprio(1);                                       \
      f32x4 s0 = mfma16(KF0, QF, zz);                                      \
      f32x4 s1 = mfma16(KF1, QF, zz);                                      \
      f32x4 s2 = mfma16(KF2, QF, zz);                                      \
      f32x4 s3 = mfma16(KF3, QF, zz);                                      \
      __builtin_amdgcn_s_setprio(0);                                       \
      float e0[4], e1[4], e2[4], e3[4];                                    \
      _Pragma("unroll")                                                    \
      for (int r = 0; r < 4; ++r) {                                        \
        e0[r] = __builtin_amdgcn_exp2f(s0[r]);                             \
        e1[r] = __builtin_amdgcn_exp2f(s1[r]);                             \
        e2[r] = __builtin_amdgcn_exp2f(s2[r]);                             \
        e3[r] = __builtin_amdgcn_exp2f(s3[r]);                             \
      }                                                                    \
      union { u32 u[4]; bf16x8 v; } A0, A1;                                \
      A0.u[0] = cvt_pk_bf16(e0[0], e0[1]);                                 \
      A0.u[1] = cvt_pk_bf16(e0[2], e0[3]);                                 \
      A0.u[2] = cvt_pk_bf16(e1[0], e1[1]);                                 \
      A0.u[3] = cvt_pk_bf16(e1[2], e1[3]);                                 \
      A1.u[0] = cvt_pk_bf16(e2[0], e2[1]);                                 \
      A1.u[1] = cvt_pk_bf16(e2[2], e2[3]);                                 \
      A1.u[2] = cvt_pk_bf16(e3[0], e3[1]);                                 \
      A1.u[3] = cvt_pk_bf16(e3[2], e3[3]);                                 \
      __builtin_amdgcn_s_setprio(1);                                       \
      ZA = mfma16(A0.v, VF00, ZA);                                         \
      ZA = mfma16(A1.v, VF01, ZA);                                         \
      ZB = mfma16(A0.v, VF10, ZB);                                         \
      ZB = mfma16(A1.v, VF11, ZB);                                         \
      ZS = mfma16(A0.v, ones.v, ZS);                                       \
      ZS = mfma16(A1.v, ones.v, ZS);                                       \
      __builtin_amdgcn_s_setprio(0);                                       \
    }

#define COMPUTE(K0, K1, K2, K3, V00, V01, V10, V11)                        \
    QFRAG(qf0, K0, K1, K2, K3, V00, V01, V10, V11, z00, z01, zs0)          \
    QFRAG(qf1, K0, K1, K2, K3, V00, V01, V10, V11, z10, z11, zs1)          \
    QFRAG(qf2, K0, K1, K2, K3, V00, V01, V10, V11, z20, z21, zs2)          \
    QFRAG(qf3, K0, K1, K2, K3, V00, V01, V10, V11, z30, z31, zs3)

  LOADT(0, ka0, ka1, ka2, ka3, va00, va01, va10, va11)
  for (int tt = 0; tt < 8; ++tt) {
    int t = tt * 2;
    LOADT(t + 1, kb0, kb1, kb2, kb3, vb00, vb01, vb10, vb11)
    COMPUTE(ka0, ka1, ka2, ka3, va00, va01, va10, va11)
    if (tt < 7) {
      LOADT(t + 2, ka0, ka1, ka2, ka3, va00, va01, va10, va11)
    }
    COMPUTE(kb0, kb1, kb2, kb3, vb00, vb01, vb10, vb11)
  }
#undef COMPUTE
#undef QFRAG
#undef LOADT

  size_t zrow = ((size_t)ks * 16 + bh) * 2048;
#define STORE(J, ZA, ZB, ZS)                                               \
  _Pragma("unroll")                                                        \
  for (int r = 0; r < 4; ++r) {                                            \
    int m = qbase + J * 16 + g * 4 + r;                                    \
    float* zp = Zp + (zrow + m) * 32;                                      \
    zp[c] = ZA[r];                                                         \
    zp[16 + c] = ZB[r];                                                    \
    if (c == 0) S[zrow + m] = ZS[r];                                       \
  }
  STORE(0, z00, z01, zs0)
  STORE(1, z10, z11, zs1)
  STORE(2, z20, z21, zs2)
  STORE(3, z30, z31, zs3)
#undef STORE
}

// ---------- kernel 4: combine(4 splits) + out = Z @ w^T + b + x_a (fp32) -------
// grid 256: block = 16 m-rows x full N=256; 4 waves, wid = 64-col slice.
__global__ __launch_bounds__(256) void out_kernel(
    const float* __restrict__ Zp, const float* __restrict__ S,
    const u16* __restrict__ W, const float* __restrict__ bias,
    const float* __restrict__ resid, float* __restrict__ out) {
  int tid = threadIdx.x, wid = tid >> 6, lane = tid & 63, g = lane >> 4, c = lane & 15;
  int m0 = blockIdx.x * 16;
  int mrow = m0 + c;
  int bq = mrow >> 11, n = mrow & 2047;
  const u16* Wp = W + (size_t)(wid * 64 + c) * 256 + g * 8;

  f32x4 acc[4] = {};
#pragma unroll
  for (int h = 0; h < 8; ++h) {
    int bh = bq * 8 + h;
    size_t sb = (size_t)bh * 2048 + n;
    float ts = (S[sb] + S[sb + 32768]) + (S[sb + 65536] + S[sb + 98304]);
    float iv = 1.0f / ts;
    const float* zp = Zp + sb * 32 + g * 8;
    float4 a0 = *(const float4*)zp;
    float4 a1 = *(const float4*)(zp + 4);
    float4 b0 = *(const float4*)(zp + 1048576);
    float4 b1 = *(const float4*)(zp + 1048576 + 4);
    float4 c0 = *(const float4*)(zp + 2097152);
    float4 c1 = *(const float4*)(zp + 2097152 + 4);
    float4 d0 = *(const float4*)(zp + 3145728);
    float4 d1 = *(const float4*)(zp + 3145728 + 4);
    float e0 = ((a0.x + b0.x) + (c0.x + d0.x)) * iv;
    float e1 = ((a0.y + b0.y) + (c0.y + d0.y)) * iv;
    float e2 = ((a0.z + b0.z) + (c0.z + d0.z)) * iv;
    float e3 = ((a0.w + b0.w) + (c0.w + d0.w)) * iv;
    float e4 = ((a1.x + b1.x) + (c1.x + d1.x)) * iv;
    float e5 = ((a1.y + b1.y) + (c1.y + d1.y)) * iv;
    float e6 = ((a1.z + b1.z) + (c1.z + d1.z)) * iv;
    float e7 = ((a1.w + b1.w) + (c1.w + d1.w)) * iv;
    union { u32 u[4]; bf16x8 v; } af;
    af.u[0] = cvt_pk_bf16(e0, e1);
    af.u[1] = cvt_pk_bf16(e2, e3);
    af.u[2] = cvt_pk_bf16(e4, e5);
    af.u[3] = cvt_pk_bf16(e6, e7);
#pragma unroll
    for (int nt = 0; nt < 4; ++nt) {
      bf16x8 bfr = *(const bf16x8*)(Wp + nt * 4096 + h * 32);
      acc[nt] = mfma16(af.v, bfr, acc[nt]);
    }
  }
#pragma unroll
  for (int nt = 0; nt < 4; ++nt) {
    int f = wid * 64 + nt * 16 + c;
    float bv = bias[f];
#pragma unroll
    for (int r = 0; r < 4; ++r) {
      int m = m0 + g * 4 + r;
      out[(size_t)m * 256 + f] = acc[nt][r] + bv + resid[(size_t)m * 256 + f];
    }
  }
}

// ---------- launch ----------
extern "C" void kernel_launch(void* const* d_in, const int* in_sizes, int n_in,
                              void* d_out, int out_size, void* d_ws, size_t ws_size,
                              hipStream_t stream) {
  const float* xa = (const float*)d_in[0];
  const float* xb = (const float*)d_in[1];
  const float* wq_w = (const float*)d_in[2];
  const float* wq_b = (const float*)d_in[3];
  const float* wka_w = (const float*)d_in[4];
  const float* wka_b = (const float*)d_in[5];
  const float* wkb_w = (const float*)d_in[6];
  const float* wkb_b = (const float*)d_in[7];
  const float* wva_w = (const float*)d_in[8];
  const float* wva_b = (const float*)d_in[9];
  const float* wvb_w = (const float*)d_in[10];
  const float* wvb_b = (const float*)d_in[11];
  const float* w_w = (const float*)d_in[12];
  const float* w_b = (const float*)d_in[13];

  u16* ws = (u16*)d_ws;
  u16* xa_bf = ws;                  // 1048576
  u16* xb_bf = ws + 1048576;        // 1048576
  u16* wbf = ws + 2097152;          // 6 * 65536
  u16* Qb = ws + 2490368;           // 1048576
  u16* Kb = ws + 3538944;           // 2097152 ([bh][4096 key][32 d], rho'd)
  u16* Vb = ws + 5636096;           // 2097152 ([bh][32 d][4096 key])
  float* Zp = (float*)(ws + 7733248);   // 4*16*2048*32 fp32 = 16 MB
  float* S = Zp + 4194304;              // 4*16*2048 fp32 = 512 KB

  convert_kernel<<<1216, 256, 0, stream>>>(xa, xb, wq_w, wka_w, wva_w, wkb_w,
                                           wvb_w, w_w, ws);
  proj_kernel<<<dim3(64, 4, 5), 256, 0, stream>>>(
      xa_bf, xb_bf, wbf, wq_b, wka_b, wva_b, wkb_b, wvb_b, Qb, Kb, Vb);
  attn_kernel<<<512, 256, 0, stream>>>(Qb, Kb, Vb, Zp, S);
  out_kernel<<<256, 256, 0, stream>>>(Zp, S, wbf + 5 * 65536, w_b, xa,
                                      (float*)d_out);
}